// Round 1
// baseline (297.114 us; speedup 1.0000x reference)
//
#include <hip/hip_runtime.h>
#include <hip/hip_bf16.h>

// Problem constants (MultiHeadAttention, B=2, S=2048, D=1024, H=16)
#define B_SZ    2
#define S_LEN   2048
#define D_MODEL 1024
#define H_NUM   16
#define DH      64
#define M_TOT   (B_SZ * S_LEN)   // 4096 tokens

typedef __attribute__((ext_vector_type(8))) short          bf16x8;
typedef __attribute__((ext_vector_type(4))) float          f32x4;
typedef __attribute__((ext_vector_type(8))) unsigned short u16x8;
typedef __attribute__((ext_vector_type(4))) unsigned short u16x4;

__device__ inline unsigned short f2bf(float f) {
  unsigned int u = __float_as_uint(f);
  u += 0x7fffu + ((u >> 16) & 1u);   // RNE (no NaN inputs here)
  return (unsigned short)(u >> 16);
}

// ---------------------------------------------------------------------------
// GEMM: C[M,N] = A[M,K] * W[N,K]^T   (torch Linear, NT layout)
// MODE 0: store C as bf16 row-major [M][N]
// MODE 1: store C transposed per-head: Vt[((b*H+h)*DH+d)*S + s]  (for PV)
// MODE 2: store C as fp32 row-major + bias (final output)
// ABF16: A is bf16 (1) or fp32 (0).  W is always fp32.
// ---------------------------------------------------------------------------
template <int MODE, int ABF16>
__global__ __launch_bounds__(256) void gemm_xwt(const void* __restrict__ Ap,
                                                const float* __restrict__ Bw,
                                                void* __restrict__ Cp,
                                                const float* __restrict__ bias) {
  __shared__ unsigned short Al[128][40];  // pitch 40 bf16 = 80B (16B multiple)
  __shared__ unsigned short Bl[128][40];

  const int tid  = threadIdx.x;
  const int lane = tid & 63;
  const int wid  = tid >> 6;
  const int wr   = wid >> 1;      // wave row (0..1)
  const int wc   = wid & 1;       // wave col (0..1)
  const int g    = lane >> 4;     // 0..3
  const int lr   = lane & 15;     // 0..15
  const int mbase = blockIdx.y * 128;
  const int nbase = blockIdx.x * 128;

  const int srow = tid >> 1;        // 0..127 staging row
  const int scol = (tid & 1) * 16;  // 0 or 16

  f32x4 acc[4][4];
#pragma unroll
  for (int i = 0; i < 4; i++)
#pragma unroll
    for (int j = 0; j < 4; j++) acc[i][j] = (f32x4){0.f, 0.f, 0.f, 0.f};

  for (int kt = 0; kt < D_MODEL / 32; ++kt) {
    // ---- stage A tile (128x32) ----
    if (ABF16) {
      const unsigned short* A = (const unsigned short*)Ap;
      const unsigned short* src =
          A + (size_t)(mbase + srow) * D_MODEL + kt * 32 + scol;
      *(u16x8*)&Al[srow][scol]     = *(const u16x8*)src;
      *(u16x8*)&Al[srow][scol + 8] = *(const u16x8*)(src + 8);
    } else {
      const float* A = (const float*)Ap;
      const float* src = A + (size_t)(mbase + srow) * D_MODEL + kt * 32 + scol;
      f32x4 f0 = *(const f32x4*)(src);
      f32x4 f1 = *(const f32x4*)(src + 4);
      f32x4 f2 = *(const f32x4*)(src + 8);
      f32x4 f3 = *(const f32x4*)(src + 12);
      unsigned short tmp[16];
#pragma unroll
      for (int i = 0; i < 4; i++) {
        tmp[i]      = f2bf(f0[i]);
        tmp[4 + i]  = f2bf(f1[i]);
        tmp[8 + i]  = f2bf(f2[i]);
        tmp[12 + i] = f2bf(f3[i]);
      }
      *(u16x8*)&Al[srow][scol]     = *(u16x8*)&tmp[0];
      *(u16x8*)&Al[srow][scol + 8] = *(u16x8*)&tmp[8];
    }
    // ---- stage W tile (128x32) ----
    {
      const float* src = Bw + (size_t)(nbase + srow) * D_MODEL + kt * 32 + scol;
      f32x4 f0 = *(const f32x4*)(src);
      f32x4 f1 = *(const f32x4*)(src + 4);
      f32x4 f2 = *(const f32x4*)(src + 8);
      f32x4 f3 = *(const f32x4*)(src + 12);
      unsigned short tmp[16];
#pragma unroll
      for (int i = 0; i < 4; i++) {
        tmp[i]      = f2bf(f0[i]);
        tmp[4 + i]  = f2bf(f1[i]);
        tmp[8 + i]  = f2bf(f2[i]);
        tmp[12 + i] = f2bf(f3[i]);
      }
      *(u16x8*)&Bl[srow][scol]     = *(u16x8*)&tmp[0];
      *(u16x8*)&Bl[srow][scol + 8] = *(u16x8*)&tmp[8];
    }
    __syncthreads();

    bf16x8 af[4], bfr[4];
#pragma unroll
    for (int i = 0; i < 4; i++) {
      af[i]  = *(const bf16x8*)&Al[wr * 64 + i * 16 + lr][g * 8];
      bfr[i] = *(const bf16x8*)&Bl[wc * 64 + i * 16 + lr][g * 8];
    }
#pragma unroll
    for (int i = 0; i < 4; i++)
#pragma unroll
      for (int j = 0; j < 4; j++)
        acc[i][j] = __builtin_amdgcn_mfma_f32_16x16x32_bf16(af[i], bfr[j],
                                                            acc[i][j], 0, 0, 0);
    __syncthreads();
  }

  // ---- epilogue ----
#pragma unroll
  for (int i = 0; i < 4; i++) {
#pragma unroll
    for (int j = 0; j < 4; j++) {
      const int mg0 = mbase + wr * 64 + i * 16 + g * 4;  // + r
      const int ng  = nbase + wc * 64 + j * 16 + lr;
      if (MODE == 0) {
        unsigned short* C = (unsigned short*)Cp;
#pragma unroll
        for (int r = 0; r < 4; r++)
          C[(size_t)(mg0 + r) * D_MODEL + ng] = f2bf(acc[i][j][r]);
      } else if (MODE == 1) {
        unsigned short* C = (unsigned short*)Cp;
        const int hh = ng >> 6, dd = ng & 63;
        const int bb = mg0 >> 11, ss = mg0 & 2047;  // mg0 mult of 4
        u16x4 pk;
#pragma unroll
        for (int r = 0; r < 4; r++) pk[r] = f2bf(acc[i][j][r]);
        *(u16x4*)&C[((size_t)((bb * H_NUM + hh) * DH + dd)) * S_LEN + ss] = pk;
      } else {
        float* C = (float*)Cp;
        const float bv = bias[ng];
#pragma unroll
        for (int r = 0; r < 4; r++)
          C[(size_t)(mg0 + r) * D_MODEL + ng] = acc[i][j][r] + bv;
      }
    }
  }
}

// ---------------------------------------------------------------------------
// Causal flash attention. Grid: (S/64, B*H). 4 waves; wave w owns 16 q-rows.
// Q,K bf16 [M][D]; V pre-transposed bf16 Vt[((b*H+h)*DH+d)*S + s].
// scale = S^-0.5 (reference reproduces the original bug).
// ---------------------------------------------------------------------------
__global__ __launch_bounds__(256) void attn_k(const unsigned short* __restrict__ qb,
                                              const unsigned short* __restrict__ kb,
                                              const unsigned short* __restrict__ vt,
                                              unsigned short* __restrict__ ctx) {
  __shared__ unsigned short Kl[64][72];      // pitch 144B (16B multiple)
  __shared__ unsigned short Vl[64][72];      // Vl[d][k]
  __shared__ unsigned short Pl[4][16][72];   // per-wave P[q][k]

  const int tid  = threadIdx.x;
  const int lane = tid & 63;
  const int w    = tid >> 6;
  const int g    = lane >> 4, lr = lane & 15;
  const int qt   = blockIdx.x;
  const int bh   = blockIdx.y;
  const int b    = bh >> 4, h = bh & 15;
  const float scale = 0.022097086912079608f;  // 2048^-0.5

  // Q fragments (held in registers for the whole kernel)
  const int qrow = b * S_LEN + qt * 64 + w * 16 + lr;
  bf16x8 qf[2];
  qf[0] = *(const bf16x8*)&qb[(size_t)qrow * D_MODEL + h * DH + g * 8];
  qf[1] = *(const bf16x8*)&qb[(size_t)qrow * D_MODEL + h * DH + 32 + g * 8];

  f32x4 cacc[4];
#pragma unroll
  for (int dc = 0; dc < 4; dc++) cacc[dc] = (f32x4){0.f, 0.f, 0.f, 0.f};
  float m_run[4], l_run[4];
#pragma unroll
  for (int r = 0; r < 4; r++) { m_run[r] = -1e30f; l_run[r] = 0.f; }

  const int srow = tid >> 2;          // 0..63
  const int scol = (tid & 3) * 16;    // 0,16,32,48

  const int nkt = qt + 1;             // causal: tiles 0..qt
  for (int kt = 0; kt < nkt; ++kt) {
    // ---- stage K (rows) and Vt (rows=d) tiles ----
    {
      const unsigned short* srcK =
          kb + (size_t)(b * S_LEN + kt * 64 + srow) * D_MODEL + h * DH + scol;
      *(u16x8*)&Kl[srow][scol]     = *(const u16x8*)srcK;
      *(u16x8*)&Kl[srow][scol + 8] = *(const u16x8*)(srcK + 8);
      const unsigned short* srcV =
          vt + ((size_t)((b * H_NUM + h) * DH + srow)) * S_LEN + kt * 64 + scol;
      *(u16x8*)&Vl[srow][scol]     = *(const u16x8*)srcV;
      *(u16x8*)&Vl[srow][scol + 8] = *(const u16x8*)(srcV + 8);
    }
    __syncthreads();

    // ---- S = Q K^T : st[kf] holds q=(g*4+r), k=kf*16+lr ----
    f32x4 st[4];
#pragma unroll
    for (int kf = 0; kf < 4; kf++) {
      bf16x8 k0 = *(const bf16x8*)&Kl[kf * 16 + lr][g * 8];
      bf16x8 k1 = *(const bf16x8*)&Kl[kf * 16 + lr][32 + g * 8];
      f32x4 z = (f32x4){0.f, 0.f, 0.f, 0.f};
      z = __builtin_amdgcn_mfma_f32_16x16x32_bf16(qf[0], k0, z, 0, 0, 0);
      z = __builtin_amdgcn_mfma_f32_16x16x32_bf16(qf[1], k1, z, 0, 0, 0);
      st[kf] = z;
    }

    // ---- scale + causal mask ----
    const int q0 = qt * 64 + w * 16 + g * 4;  // + r (global q)
#pragma unroll
    for (int kf = 0; kf < 4; kf++) {
      const int kg = kt * 64 + kf * 16 + lr;  // global k
#pragma unroll
      for (int r = 0; r < 4; r++) {
        const float v = st[kf][r] * scale;
        st[kf][r] = (kg > q0 + r) ? -1e30f : v;
      }
    }

    // ---- online softmax: row max ----
    f32x4 rm = st[0];
#pragma unroll
    for (int kf = 1; kf < 4; kf++)
#pragma unroll
      for (int r = 0; r < 4; r++) rm[r] = fmaxf(rm[r], st[kf][r]);
#pragma unroll
    for (int mk = 1; mk < 16; mk <<= 1)
#pragma unroll
      for (int r = 0; r < 4; r++)
        rm[r] = fmaxf(rm[r], __shfl_xor(rm[r], mk, 64));

    float alpha[4];
#pragma unroll
    for (int r = 0; r < 4; r++) {
      const float mnew = fmaxf(m_run[r], rm[r]);
      alpha[r]  = __expf(m_run[r] - mnew);
      m_run[r]  = mnew;
    }

    // ---- P = exp(st - m), row sum ----
    f32x4 rs = (f32x4){0.f, 0.f, 0.f, 0.f};
#pragma unroll
    for (int kf = 0; kf < 4; kf++)
#pragma unroll
      for (int r = 0; r < 4; r++) {
        const float p = __expf(st[kf][r] - m_run[r]);
        st[kf][r] = p;
        rs[r] += p;
      }
#pragma unroll
    for (int mk = 1; mk < 16; mk <<= 1)
#pragma unroll
      for (int r = 0; r < 4; r++) rs[r] += __shfl_xor(rs[r], mk, 64);
#pragma unroll
    for (int r = 0; r < 4; r++) l_run[r] = l_run[r] * alpha[r] + rs[r];

    // ---- rescale running context ----
#pragma unroll
    for (int dc = 0; dc < 4; dc++)
#pragma unroll
      for (int r = 0; r < 4; r++) cacc[dc][r] *= alpha[r];

    // ---- P -> per-wave LDS (re-fragment for PV) ----
#pragma unroll
    for (int kf = 0; kf < 4; kf++)
#pragma unroll
      for (int r = 0; r < 4; r++)
        Pl[w][g * 4 + r][kf * 16 + lr] = f2bf(st[kf][r]);

    // ---- ctx += P V  (A-frag from Pl rows, B-frag from Vl rows) ----
#pragma unroll
    for (int ks = 0; ks < 2; ks++) {
      bf16x8 pa = *(const bf16x8*)&Pl[w][lr][ks * 32 + g * 8];
#pragma unroll
      for (int dc = 0; dc < 4; dc++) {
        bf16x8 vb = *(const bf16x8*)&Vl[dc * 16 + lr][ks * 32 + g * 8];
        cacc[dc] =
            __builtin_amdgcn_mfma_f32_16x16x32_bf16(pa, vb, cacc[dc], 0, 0, 0);
      }
    }
    __syncthreads();
  }

  // ---- normalize + store ctx (bf16) ----
  float inv[4];
#pragma unroll
  for (int r = 0; r < 4; r++) inv[r] = 1.0f / l_run[r];
  const int orow0 = b * S_LEN + qt * 64 + w * 16 + g * 4;
#pragma unroll
  for (int dc = 0; dc < 4; dc++)
#pragma unroll
    for (int r = 0; r < 4; r++)
      ctx[(size_t)(orow0 + r) * D_MODEL + h * DH + dc * 16 + lr] =
          f2bf(cacc[dc][r] * inv[r]);
}

// ---------------------------------------------------------------------------
extern "C" void kernel_launch(void* const* d_in, const int* in_sizes, int n_in,
                              void* d_out, int out_size, void* d_ws,
                              size_t ws_size, hipStream_t stream) {
  const float* x  = (const float*)d_in[0];
  const float* Wq = (const float*)d_in[1];
  const float* Wk = (const float*)d_in[2];
  const float* Wv = (const float*)d_in[3];
  const float* Wo = (const float*)d_in[4];
  const float* bo = (const float*)d_in[5];
  float* out = (float*)d_out;

  // workspace: Q, K, Vt, ctx as bf16 — 4 * 8 MiB = 32 MiB
  unsigned short* qb = (unsigned short*)d_ws;
  unsigned short* kb = qb + (size_t)M_TOT * D_MODEL;
  unsigned short* vt = kb + (size_t)M_TOT * D_MODEL;
  unsigned short* cx = vt + (size_t)M_TOT * D_MODEL;

  dim3 gg(D_MODEL / 128, M_TOT / 128);  // 8 x 32 = 256 blocks
  hipLaunchKernelGGL((gemm_xwt<0, 0>), gg, dim3(256), 0, stream, x, Wq, qb, nullptr);
  hipLaunchKernelGGL((gemm_xwt<0, 0>), gg, dim3(256), 0, stream, x, Wk, kb, nullptr);
  hipLaunchKernelGGL((gemm_xwt<1, 0>), gg, dim3(256), 0, stream, x, Wv, vt, nullptr);
  hipLaunchKernelGGL(attn_k, dim3(S_LEN / 64, B_SZ * H_NUM), dim3(256), 0,
                     stream, qb, kb, vt, cx);
  hipLaunchKernelGGL((gemm_xwt<2, 1>), gg, dim3(256), 0, stream, cx, Wo, out, bo);
}

// Round 2
// 198.343 us; speedup vs baseline: 1.4980x; 1.4980x over previous
//
#include <hip/hip_runtime.h>
#include <hip/hip_bf16.h>

// Problem constants (MultiHeadAttention, B=2, S=2048, D=1024, H=16)
#define B_SZ    2
#define S_LEN   2048
#define D_MODEL 1024
#define H_NUM   16
#define DH      64
#define M_TOT   (B_SZ * S_LEN)   // 4096 tokens

typedef __attribute__((ext_vector_type(8))) short          bf16x8;
typedef __attribute__((ext_vector_type(4))) float          f32x4;
typedef __attribute__((ext_vector_type(8))) unsigned short u16x8;
typedef __attribute__((ext_vector_type(4))) unsigned short u16x4;

__device__ inline unsigned short f2bf(float f) {
  unsigned int u = __float_as_uint(f);
  u += 0x7fffu + ((u >> 16) & 1u);   // RNE (no NaN inputs here)
  return (unsigned short)(u >> 16);
}

// async global->LDS, 16B per lane. LDS dest = wave-uniform base + lane*16.
__device__ inline void gload16(const void* g, void* l) {
  __builtin_amdgcn_global_load_lds(
      (const __attribute__((address_space(1))) void*)g,
      (__attribute__((address_space(3))) void*)l, 16, 0, 0);
}

// ---------------------------------------------------------------------------
// fp32 -> bf16 conversion for x, Wq, Wk, Wv, Wo (8M elements, 8 per thread)
// ---------------------------------------------------------------------------
__global__ __launch_bounds__(256) void to_bf16_all(
    const float* __restrict__ x, const float* __restrict__ wq,
    const float* __restrict__ wk, const float* __restrict__ wv,
    const float* __restrict__ wo, unsigned short* __restrict__ xb,
    unsigned short* __restrict__ wqb, unsigned short* __restrict__ wkb,
    unsigned short* __restrict__ wvb, unsigned short* __restrict__ wob) {
  const size_t i = ((size_t)blockIdx.x * 256 + threadIdx.x) * 8;
  const float* src;
  unsigned short* dst;
  size_t off;
  if (i < 4194304)      { src = x;  dst = xb;  off = i; }
  else if (i < 5242880) { src = wq; dst = wqb; off = i - 4194304; }
  else if (i < 6291456) { src = wk; dst = wkb; off = i - 5242880; }
  else if (i < 7340032) { src = wv; dst = wvb; off = i - 6291456; }
  else                  { src = wo; dst = wob; off = i - 7340032; }
  f32x4 a = *(const f32x4*)(src + off);
  f32x4 b = *(const f32x4*)(src + off + 4);
  u16x8 o;
#pragma unroll
  for (int j = 0; j < 4; j++) { o[j] = f2bf(a[j]); o[4 + j] = f2bf(b[j]); }
  *(u16x8*)(dst + off) = o;
}

// ---------------------------------------------------------------------------
// bf16 NT-GEMM core: acc += A[128 rows @ mbase] * W[128 rows @ nbase]^T,
// K = D_MODEL. global_load_lds(16) staging, linear LDS + XOR chunk swizzle
// (pre-swizzled source, swizzled read).
// ---------------------------------------------------------------------------
__device__ __forceinline__ void gemm_core(const unsigned short* __restrict__ A,
                                          const unsigned short* __restrict__ W,
                                          unsigned short (*Al)[32],
                                          unsigned short (*Bl)[32], int mbase,
                                          int nbase, f32x4 acc[4][4]) {
  const int tid  = threadIdx.x;
  const int lane = tid & 63;
  const int wid  = tid >> 6;
  const int wr   = wid >> 1, wc = wid & 1;
  const int g    = lane >> 4, lr = lane & 15;

  // staging: thread t covers LDS row (t>>2) [+64 for issue 1], 16B chunk (t&3)
  // LDS slot (r,c) holds global chunk c ^ ((r>>1)&3)  -> source chunk:
  const int r0 = tid >> 2;                        // 0..63
  const int cg = (tid & 3) ^ ((tid >> 3) & 3);    // swizzled source chunk

  char* ldsA = (char*)&Al[0][0] + wid * 1024;
  char* ldsB = (char*)&Bl[0][0] + wid * 1024;

  for (int kt = 0; kt < D_MODEL / 32; ++kt) {
    const unsigned short* As =
        A + (size_t)(mbase + r0) * D_MODEL + kt * 32 + cg * 8;
    const unsigned short* Ws =
        W + (size_t)(nbase + r0) * D_MODEL + kt * 32 + cg * 8;
    gload16(As, ldsA);
    gload16(As + (size_t)64 * D_MODEL, ldsA + 4096);
    gload16(Ws, ldsB);
    gload16(Ws + (size_t)64 * D_MODEL, ldsB + 4096);
    __syncthreads();

    bf16x8 af[4], bfr[4];
#pragma unroll
    for (int i = 0; i < 4; i++) {
      const int ra = wr * 64 + i * 16 + lr;
      af[i] = *(const bf16x8*)&Al[ra][(g ^ ((ra >> 1) & 3)) * 8];
      const int rb = wc * 64 + i * 16 + lr;
      bfr[i] = *(const bf16x8*)&Bl[rb][(g ^ ((rb >> 1) & 3)) * 8];
    }
#pragma unroll
    for (int i = 0; i < 4; i++)
#pragma unroll
      for (int j = 0; j < 4; j++)
        acc[i][j] = __builtin_amdgcn_mfma_f32_16x16x32_bf16(af[i], bfr[j],
                                                            acc[i][j], 0, 0, 0);
    __syncthreads();
  }
}

// ---------------------------------------------------------------------------
// Fused Q/K/V projection. grid (N/128, M/128, 3); z picks weight + epilogue.
// z=0 -> Q bf16 [M][D]; z=1 -> K bf16 [M][D]; z=2 -> V transposed
// Vt[((b*H+h)*DH+d)*S + s].
// ---------------------------------------------------------------------------
__global__ __launch_bounds__(256) void gemm_qkv(
    const unsigned short* __restrict__ xb, const unsigned short* __restrict__ wqb,
    const unsigned short* __restrict__ wkb, const unsigned short* __restrict__ wvb,
    unsigned short* __restrict__ qb, unsigned short* __restrict__ kb,
    unsigned short* __restrict__ vt) {
  __shared__ unsigned short Al[128][32];
  __shared__ unsigned short Bl[128][32];
  const int z = blockIdx.z;
  const unsigned short* W = (z == 0) ? wqb : (z == 1) ? wkb : wvb;
  unsigned short* dst = (z == 0) ? qb : (z == 1) ? kb : vt;

  f32x4 acc[4][4];
#pragma unroll
  for (int i = 0; i < 4; i++)
#pragma unroll
    for (int j = 0; j < 4; j++) acc[i][j] = (f32x4){0.f, 0.f, 0.f, 0.f};

  const int mbase = blockIdx.y * 128, nbase = blockIdx.x * 128;
  gemm_core(xb, W, Al, Bl, mbase, nbase, acc);

  const int lane = threadIdx.x & 63, wid = threadIdx.x >> 6;
  const int wr = wid >> 1, wc = wid & 1, g = lane >> 4, lr = lane & 15;
#pragma unroll
  for (int i = 0; i < 4; i++) {
#pragma unroll
    for (int j = 0; j < 4; j++) {
      const int mg0 = mbase + wr * 64 + i * 16 + g * 4;  // + r
      const int ng  = nbase + wc * 64 + j * 16 + lr;
      if (z < 2) {
#pragma unroll
        for (int r = 0; r < 4; r++)
          dst[(size_t)(mg0 + r) * D_MODEL + ng] = f2bf(acc[i][j][r]);
      } else {
        const int hh = ng >> 6, dd = ng & 63;
        const int bb = mg0 >> 11, ss = mg0 & 2047;  // mg0 mult of 4
        u16x4 pk;
#pragma unroll
        for (int r = 0; r < 4; r++) pk[r] = f2bf(acc[i][j][r]);
        *(u16x4*)&dst[((size_t)((bb * H_NUM + hh) * DH + dd)) * S_LEN + ss] = pk;
      }
    }
  }
}

// ---------------------------------------------------------------------------
// Output projection: out[M][D] fp32 = cx * Wo^T + bo
// ---------------------------------------------------------------------------
__global__ __launch_bounds__(256) void gemm_out(
    const unsigned short* __restrict__ cx, const unsigned short* __restrict__ wob,
    float* __restrict__ out, const float* __restrict__ bo) {
  __shared__ unsigned short Al[128][32];
  __shared__ unsigned short Bl[128][32];
  f32x4 acc[4][4];
#pragma unroll
  for (int i = 0; i < 4; i++)
#pragma unroll
    for (int j = 0; j < 4; j++) acc[i][j] = (f32x4){0.f, 0.f, 0.f, 0.f};

  const int mbase = blockIdx.y * 128, nbase = blockIdx.x * 128;
  gemm_core(cx, wob, Al, Bl, mbase, nbase, acc);

  const int lane = threadIdx.x & 63, wid = threadIdx.x >> 6;
  const int wr = wid >> 1, wc = wid & 1, g = lane >> 4, lr = lane & 15;
#pragma unroll
  for (int i = 0; i < 4; i++) {
#pragma unroll
    for (int j = 0; j < 4; j++) {
      const int mg0 = mbase + wr * 64 + i * 16 + g * 4;
      const int ng  = nbase + wc * 64 + j * 16 + lr;
      const float bv = bo[ng];
#pragma unroll
      for (int r = 0; r < 4; r++)
        out[(size_t)(mg0 + r) * D_MODEL + ng] = acc[i][j][r] + bv;
    }
  }
}

// ---------------------------------------------------------------------------
// Causal flash attention. grid (S/128, B*H); 4 waves, each owns 32 q-rows.
// K/V staged via global_load_lds with XOR swizzle; P re-fragmented through
// per-wave LDS. q-tiles processed in reverse order (longest blocks first).
// scale = S^-0.5 (faithful reproduction of the reference's scale bug).
// ---------------------------------------------------------------------------
__global__ __launch_bounds__(256) void attn_k(
    const unsigned short* __restrict__ qb, const unsigned short* __restrict__ kb,
    const unsigned short* __restrict__ vt, unsigned short* __restrict__ ctx) {
  __shared__ unsigned short Kl[64][64];     // linear, XOR-swizzled chunks
  __shared__ unsigned short Vl[64][64];     // Vl[d][k], swizzled
  __shared__ unsigned short Pl[4][32][72];  // per-wave P[q][k], padded pitch

  const int tid  = threadIdx.x;
  const int lane = tid & 63;
  const int w    = tid >> 6;
  const int g    = lane >> 4, lr = lane & 15;
  const int qtile = (int)(gridDim.x - 1 - blockIdx.x);  // reverse: 15..0
  const int bh   = blockIdx.y;
  const int b    = bh >> 4, h = bh & 15;
  const float scale = 0.022097086912079608f;  // 2048^-0.5

  // Q fragments: rows qtile*128 + w*32 + f*16 + lr, k-slices ks*32+g*8
  const size_t qbase = (size_t)(b * S_LEN + qtile * 128 + w * 32 + lr) * D_MODEL
                       + h * DH;
  bf16x8 qf[2][2];
#pragma unroll
  for (int f = 0; f < 2; f++)
#pragma unroll
    for (int ks = 0; ks < 2; ks++)
      qf[f][ks] = *(const bf16x8*)&qb[qbase + (size_t)f * 16 * D_MODEL +
                                      ks * 32 + g * 8];

  f32x4 cacc[2][4];
#pragma unroll
  for (int f = 0; f < 2; f++)
#pragma unroll
    for (int dc = 0; dc < 4; dc++) cacc[f][dc] = (f32x4){0.f, 0.f, 0.f, 0.f};
  float m_run[2][4], l_run[2][4];
#pragma unroll
  for (int f = 0; f < 2; f++)
#pragma unroll
    for (int r = 0; r < 4; r++) { m_run[f][r] = -1e30f; l_run[f][r] = 0.f; }

  // staging: row (t>>3) [+32 issue1], chunk slot t&7; slot holds global chunk
  // slot ^ (row&7)  ->  source chunk:
  const int sr  = tid >> 3;                      // 0..31
  const int scg = (tid & 7) ^ ((tid >> 3) & 7);  // swizzled source chunk
  char* ldsK = (char*)&Kl[0][0] + w * 1024;
  char* ldsV = (char*)&Vl[0][0] + w * 1024;

  const int nkt = 2 * qtile + 2;  // causal tile count
  for (int kt = 0; kt < nkt; ++kt) {
    const unsigned short* srcK =
        kb + (size_t)(b * S_LEN + kt * 64 + sr) * D_MODEL + h * DH + scg * 8;
    const unsigned short* srcV =
        vt + ((size_t)((b * H_NUM + h) * DH + sr)) * S_LEN + kt * 64 + scg * 8;
    gload16(srcK, ldsK);
    gload16(srcK + (size_t)32 * D_MODEL, ldsK + 4096);
    gload16(srcV, ldsV);
    gload16(srcV + (size_t)32 * S_LEN, ldsV + 4096);
    __syncthreads();

    // ---- per-f: S = Q K^T, mask, online softmax, P -> LDS ----
#pragma unroll
    for (int f = 0; f < 2; f++) {
      f32x4 st[4];
#pragma unroll
      for (int kf = 0; kf < 4; kf++) {
        const int rk = kf * 16 + lr;
        bf16x8 k0 = *(const bf16x8*)&Kl[rk][((g) ^ (rk & 7)) * 8];
        bf16x8 k1 = *(const bf16x8*)&Kl[rk][((4 + g) ^ (rk & 7)) * 8];
        f32x4 z = (f32x4){0.f, 0.f, 0.f, 0.f};
        z = __builtin_amdgcn_mfma_f32_16x16x32_bf16(qf[f][0], k0, z, 0, 0, 0);
        z = __builtin_amdgcn_mfma_f32_16x16x32_bf16(qf[f][1], k1, z, 0, 0, 0);
        st[kf] = z;
      }

      const int q0 = qtile * 128 + w * 32 + f * 16 + g * 4;
#pragma unroll
      for (int kf = 0; kf < 4; kf++) {
        const int kg = kt * 64 + kf * 16 + lr;
#pragma unroll
        for (int r = 0; r < 4; r++) {
          const float v = st[kf][r] * scale;
          st[kf][r] = (kg > q0 + r) ? -1e30f : v;
        }
      }

      f32x4 rm = st[0];
#pragma unroll
      for (int kf = 1; kf < 4; kf++)
#pragma unroll
        for (int r = 0; r < 4; r++) rm[r] = fmaxf(rm[r], st[kf][r]);
#pragma unroll
      for (int mk = 1; mk < 16; mk <<= 1)
#pragma unroll
        for (int r = 0; r < 4; r++)
          rm[r] = fmaxf(rm[r], __shfl_xor(rm[r], mk, 64));

      float alpha[4];
#pragma unroll
      for (int r = 0; r < 4; r++) {
        const float mnew = fmaxf(m_run[f][r], rm[r]);
        alpha[r]     = __expf(m_run[f][r] - mnew);
        m_run[f][r]  = mnew;
      }

      f32x4 rs = (f32x4){0.f, 0.f, 0.f, 0.f};
#pragma unroll
      for (int kf = 0; kf < 4; kf++)
#pragma unroll
        for (int r = 0; r < 4; r++) {
          const float p = __expf(st[kf][r] - m_run[f][r]);
          st[kf][r] = p;
          rs[r] += p;
        }
#pragma unroll
      for (int mk = 1; mk < 16; mk <<= 1)
#pragma unroll
        for (int r = 0; r < 4; r++) rs[r] += __shfl_xor(rs[r], mk, 64);
#pragma unroll
      for (int r = 0; r < 4; r++)
        l_run[f][r] = l_run[f][r] * alpha[r] + rs[r];

#pragma unroll
      for (int dc = 0; dc < 4; dc++)
#pragma unroll
        for (int r = 0; r < 4; r++) cacc[f][dc][r] *= alpha[r];

#pragma unroll
      for (int kf = 0; kf < 4; kf++)
#pragma unroll
        for (int r = 0; r < 4; r++)
          Pl[w][f * 16 + g * 4 + r][kf * 16 + lr] = f2bf(st[kf][r]);
    }

    // ---- ctx += P V ----
#pragma unroll
    for (int ks = 0; ks < 2; ks++) {
      bf16x8 vb[4];
#pragma unroll
      for (int dc = 0; dc < 4; dc++) {
        const int rv = dc * 16 + lr;
        vb[dc] = *(const bf16x8*)&Vl[rv][((ks * 4 + g) ^ (rv & 7)) * 8];
      }
#pragma unroll
      for (int f = 0; f < 2; f++) {
        bf16x8 pa = *(const bf16x8*)&Pl[w][f * 16 + lr][ks * 32 + g * 8];
#pragma unroll
        for (int dc = 0; dc < 4; dc++)
          cacc[f][dc] = __builtin_amdgcn_mfma_f32_16x16x32_bf16(
              pa, vb[dc], cacc[f][dc], 0, 0, 0);
      }
    }
    __syncthreads();
  }

  // ---- normalize + store ctx (bf16) ----
#pragma unroll
  for (int f = 0; f < 2; f++) {
    float inv[4];
#pragma unroll
    for (int r = 0; r < 4; r++) inv[r] = 1.0f / l_run[f][r];
    const int orow0 = b * S_LEN + qtile * 128 + w * 32 + f * 16 + g * 4;
#pragma unroll
    for (int dc = 0; dc < 4; dc++)
#pragma unroll
      for (int r = 0; r < 4; r++)
        ctx[(size_t)(orow0 + r) * D_MODEL + h * DH + dc * 16 + lr] =
            f2bf(cacc[f][dc][r] * inv[r]);
  }
}

// ---------------------------------------------------------------------------
extern "C" void kernel_launch(void* const* d_in, const int* in_sizes, int n_in,
                              void* d_out, int out_size, void* d_ws,
                              size_t ws_size, hipStream_t stream) {
  const float* x  = (const float*)d_in[0];
  const float* Wq = (const float*)d_in[1];
  const float* Wk = (const float*)d_in[2];
  const float* Wv = (const float*)d_in[3];
  const float* Wo = (const float*)d_in[4];
  const float* bo = (const float*)d_in[5];
  float* out = (float*)d_out;

  // workspace (bf16 elements): xb 4M | wqb,wkb,wvb,wob 1M each | qb,kb,vt,cx 4M
  unsigned short* xb  = (unsigned short*)d_ws;
  unsigned short* wqb = xb  + (size_t)M_TOT * D_MODEL;
  unsigned short* wkb = wqb + (size_t)D_MODEL * D_MODEL;
  unsigned short* wvb = wkb + (size_t)D_MODEL * D_MODEL;
  unsigned short* wob = wvb + (size_t)D_MODEL * D_MODEL;
  unsigned short* qb  = wob + (size_t)D_MODEL * D_MODEL;
  unsigned short* kb  = qb  + (size_t)M_TOT * D_MODEL;
  unsigned short* vt  = kb  + (size_t)M_TOT * D_MODEL;
  unsigned short* cx  = vt  + (size_t)M_TOT * D_MODEL;

  to_bf16_all<<<4096, 256, 0, stream>>>(x, Wq, Wk, Wv, Wo, xb, wqb, wkb, wvb,
                                        wob);
  gemm_qkv<<<dim3(D_MODEL / 128, M_TOT / 128, 3), 256, 0, stream>>>(
      xb, wqb, wkb, wvb, qb, kb, vt);
  attn_k<<<dim3(S_LEN / 128, B_SZ * H_NUM), 256, 0, stream>>>(qb, kb, vt, cx);
  gemm_out<<<dim3(D_MODEL / 128, M_TOT / 128), 256, 0, stream>>>(cx, wob, out,
                                                                 bo);
}

// Round 4
// 137.985 us; speedup vs baseline: 2.1532x; 1.4374x over previous
//
#include <hip/hip_runtime.h>
#include <hip/hip_bf16.h>

// Problem constants (MultiHeadAttention, B=2, S=2048, D=1024, H=16)
#define B_SZ    2
#define S_LEN   2048
#define D_MODEL 1024
#define H_NUM   16
#define DH      64
#define M_TOT   (B_SZ * S_LEN)   // 4096 tokens

// scale = S^-0.5 (faithful bug) folded with log2(e) for exp2-domain softmax
#define QSCALE (0.022097086912079608f * 1.4426950408889634f)

typedef __attribute__((ext_vector_type(8)))  short          bf16x8;
typedef __attribute__((ext_vector_type(4)))  float          f32x4;
typedef __attribute__((ext_vector_type(16))) float          f32x16;
typedef __attribute__((ext_vector_type(8)))  unsigned short u16x8;
typedef __attribute__((ext_vector_type(4)))  unsigned short u16x4;

__device__ inline unsigned short f2bf(float f) {
  unsigned int u = __float_as_uint(f);
  u += 0x7fffu + ((u >> 16) & 1u);   // RNE (no NaN inputs here)
  return (unsigned short)(u >> 16);
}

__device__ inline float fexp2(float x) {
#if __has_builtin(__builtin_amdgcn_exp2f)
  return __builtin_amdgcn_exp2f(x);
#else
  return exp2f(x);
#endif
}

__device__ inline unsigned cvt_pk_bf16(float lo, float hi) {
  unsigned r;
  asm("v_cvt_pk_bf16_f32 %0, %1, %2" : "=v"(r) : "v"(lo), "v"(hi));
  return r;
}

// async global->LDS, 16B per lane. LDS dest = wave-uniform base + lane*16.
__device__ inline void gload16(const void* g, void* l) {
  __builtin_amdgcn_global_load_lds(
      (const __attribute__((address_space(1))) void*)g,
      (__attribute__((address_space(3))) void*)l, 16, 0, 0);
}

// ---------------------------------------------------------------------------
// fp32 -> bf16 conversion for x, Wq, Wk, Wv, Wo (8M elements, 8 per thread)
// ---------------------------------------------------------------------------
__global__ __launch_bounds__(256) void to_bf16_all(
    const float* __restrict__ x, const float* __restrict__ wq,
    const float* __restrict__ wk, const float* __restrict__ wv,
    const float* __restrict__ wo, unsigned short* __restrict__ xb,
    unsigned short* __restrict__ wqb, unsigned short* __restrict__ wkb,
    unsigned short* __restrict__ wvb, unsigned short* __restrict__ wob) {
  const size_t i = ((size_t)blockIdx.x * 256 + threadIdx.x) * 8;
  const float* src;
  unsigned short* dst;
  size_t off;
  if (i < 4194304)      { src = x;  dst = xb;  off = i; }
  else if (i < 5242880) { src = wq; dst = wqb; off = i - 4194304; }
  else if (i < 6291456) { src = wk; dst = wkb; off = i - 5242880; }
  else if (i < 7340032) { src = wv; dst = wvb; off = i - 6291456; }
  else                  { src = wo; dst = wob; off = i - 7340032; }
  f32x4 a = *(const f32x4*)(src + off);
  f32x4 b = *(const f32x4*)(src + off + 4);
  u16x8 o;
#pragma unroll
  for (int j = 0; j < 4; j++) { o[j] = f2bf(a[j]); o[4 + j] = f2bf(b[j]); }
  *(u16x8*)(dst + off) = o;
}

// ---------------------------------------------------------------------------
// bf16 NT-GEMM core: acc += A[128 rows @ mbase] * W[128 rows @ nbase]^T,
// K = D_MODEL. global_load_lds(16) staging, linear LDS + XOR chunk swizzle.
// ---------------------------------------------------------------------------
__device__ __forceinline__ void gemm_core(const unsigned short* __restrict__ A,
                                          const unsigned short* __restrict__ W,
                                          unsigned short (*Al)[32],
                                          unsigned short (*Bl)[32], int mbase,
                                          int nbase, f32x4 acc[4][4]) {
  const int tid  = threadIdx.x;
  const int lane = tid & 63;
  const int wid  = tid >> 6;
  const int wr   = wid >> 1, wc = wid & 1;
  const int g    = lane >> 4, lr = lane & 15;

  const int r0 = tid >> 2;                        // 0..63
  const int cg = (tid & 3) ^ ((tid >> 3) & 3);    // swizzled source chunk

  char* ldsA = (char*)&Al[0][0] + wid * 1024;
  char* ldsB = (char*)&Bl[0][0] + wid * 1024;

  for (int kt = 0; kt < D_MODEL / 32; ++kt) {
    const unsigned short* As =
        A + (size_t)(mbase + r0) * D_MODEL + kt * 32 + cg * 8;
    const unsigned short* Ws =
        W + (size_t)(nbase + r0) * D_MODEL + kt * 32 + cg * 8;
    gload16(As, ldsA);
    gload16(As + (size_t)64 * D_MODEL, ldsA + 4096);
    gload16(Ws, ldsB);
    gload16(Ws + (size_t)64 * D_MODEL, ldsB + 4096);
    __syncthreads();

    bf16x8 af[4], bfr[4];
#pragma unroll
    for (int i = 0; i < 4; i++) {
      const int ra = wr * 64 + i * 16 + lr;
      af[i] = *(const bf16x8*)&Al[ra][(g ^ ((ra >> 1) & 3)) * 8];
      const int rb = wc * 64 + i * 16 + lr;
      bfr[i] = *(const bf16x8*)&Bl[rb][(g ^ ((rb >> 1) & 3)) * 8];
    }
#pragma unroll
    for (int i = 0; i < 4; i++)
#pragma unroll
      for (int j = 0; j < 4; j++)
        acc[i][j] = __builtin_amdgcn_mfma_f32_16x16x32_bf16(af[i], bfr[j],
                                                            acc[i][j], 0, 0, 0);
    __syncthreads();
  }
}

// ---------------------------------------------------------------------------
// Fused Q/K/V projection. grid (N/128, M/128, 3); z picks weight + epilogue.
// z=0 -> Q bf16 [M][D] PRE-SCALED by QSCALE; z=1 -> K bf16 [M][D];
// z=2 -> V transposed Vt[((b*H+h)*DH+d)*S + s].
// ---------------------------------------------------------------------------
__global__ __launch_bounds__(256) void gemm_qkv(
    const unsigned short* __restrict__ xb, const unsigned short* __restrict__ wqb,
    const unsigned short* __restrict__ wkb, const unsigned short* __restrict__ wvb,
    unsigned short* __restrict__ qb, unsigned short* __restrict__ kb,
    unsigned short* __restrict__ vt) {
  __shared__ unsigned short Al[128][32];
  __shared__ unsigned short Bl[128][32];
  const int z = blockIdx.z;
  const unsigned short* W = (z == 0) ? wqb : (z == 1) ? wkb : wvb;
  unsigned short* dst = (z == 0) ? qb : (z == 1) ? kb : vt;
  const float sc = (z == 0) ? QSCALE : 1.0f;

  f32x4 acc[4][4];
#pragma unroll
  for (int i = 0; i < 4; i++)
#pragma unroll
    for (int j = 0; j < 4; j++) acc[i][j] = (f32x4){0.f, 0.f, 0.f, 0.f};

  const int mbase = blockIdx.y * 128, nbase = blockIdx.x * 128;
  gemm_core(xb, W, Al, Bl, mbase, nbase, acc);

  const int lane = threadIdx.x & 63, wid = threadIdx.x >> 6;
  const int wr = wid >> 1, wc = wid & 1, g = lane >> 4, lr = lane & 15;
#pragma unroll
  for (int i = 0; i < 4; i++) {
#pragma unroll
    for (int j = 0; j < 4; j++) {
      const int mg0 = mbase + wr * 64 + i * 16 + g * 4;  // + r
      const int ng  = nbase + wc * 64 + j * 16 + lr;
      if (z < 2) {
#pragma unroll
        for (int r = 0; r < 4; r++)
          dst[(size_t)(mg0 + r) * D_MODEL + ng] = f2bf(acc[i][j][r] * sc);
      } else {
        const int hh = ng >> 6, dd = ng & 63;
        const int bb = mg0 >> 11, ss = mg0 & 2047;  // mg0 mult of 4
        u16x4 pk;
#pragma unroll
        for (int r = 0; r < 4; r++) pk[r] = f2bf(acc[i][j][r]);
        *(u16x4*)&dst[((size_t)((bb * H_NUM + hh) * DH + dd)) * S_LEN + ss] = pk;
      }
    }
  }
}

// ---------------------------------------------------------------------------
// Output projection: out[M][D] fp32 = cx * Wo^T + bo
// ---------------------------------------------------------------------------
__global__ __launch_bounds__(256) void gemm_out(
    const unsigned short* __restrict__ cx, const unsigned short* __restrict__ wob,
    float* __restrict__ out, const float* __restrict__ bo) {
  __shared__ unsigned short Al[128][32];
  __shared__ unsigned short Bl[128][32];
  f32x4 acc[4][4];
#pragma unroll
  for (int i = 0; i < 4; i++)
#pragma unroll
    for (int j = 0; j < 4; j++) acc[i][j] = (f32x4){0.f, 0.f, 0.f, 0.f};

  const int mbase = blockIdx.y * 128, nbase = blockIdx.x * 128;
  gemm_core(cx, wob, Al, Bl, mbase, nbase, acc);

  const int lane = threadIdx.x & 63, wid = threadIdx.x >> 6;
  const int wr = wid >> 1, wc = wid & 1, g = lane >> 4, lr = lane & 15;
#pragma unroll
  for (int i = 0; i < 4; i++) {
#pragma unroll
    for (int j = 0; j < 4; j++) {
      const int mg0 = mbase + wr * 64 + i * 16 + g * 4;
      const int ng  = nbase + wc * 64 + j * 16 + lr;
      const float bv = bo[ng];
#pragma unroll
      for (int r = 0; r < 4; r++)
        out[(size_t)(mg0 + r) * D_MODEL + ng] = acc[i][j][r] + bv;
    }
  }
}

// ---------------------------------------------------------------------------
// Causal flash attention, swapped-operand 32x32 structure.
// grid = 512 1-D blocks; 4 waves/block, each wave owns 32 q-rows.
// bid<256 -> qtiles 8..15, bid>=256 -> qtiles 7..0 (balanced CU pairing).
// S^T = mfma(K, Q): lane owns full P-row of q = lane&31 (with partner l^32).
// ctx^T = mfma(Vt, P): normalize/rescale are per-lane scalars.
// Q pre-scaled by S^-0.5 * log2(e); softmax in exp2 domain; defer-max THR=8.
// ---------------------------------------------------------------------------
__global__ __launch_bounds__(256) void attn_v3(
    const unsigned short* __restrict__ qb, const unsigned short* __restrict__ kb,
    const unsigned short* __restrict__ vt, unsigned short* __restrict__ cx) {
  __shared__ unsigned short Kl[2][64][64];  // [buf][kv][dh], XOR-swizzled chunks
  __shared__ unsigned short Vl[2][64][64];  // [buf][d][kv], XOR-swizzled chunks
  __shared__ unsigned short Tl[4][32][72];  // per-wave ctx transpose buffer

  const int tid  = threadIdx.x;
  const int lane = tid & 63;
  const int w    = tid >> 6;
  const int hi   = lane >> 5;
  const int lq   = lane & 31;
  const int bid  = blockIdx.x;
  const int qi   = (bid < 256) ? (8 + (bid >> 5)) : (7 - ((bid - 256) >> 5));
  const int bh   = bid & 31;
  const int b    = bh >> 4, h = bh & 15;

  const int qg0  = qi * 128 + w * 32;   // warp's q base within sequence
  const int tok0 = b * S_LEN + qg0;

  // staging indices: thread t -> row t>>3 (+32), chunk t&7; src chunk swizzled
  const int sr  = tid >> 3;
  const int scg = (tid & 7) ^ (sr & 7);
  const unsigned short* kbase =
      kb + (size_t)(b * S_LEN) * D_MODEL + h * DH + scg * 8;
  const unsigned short* vrow =
      vt + ((size_t)((b * H_NUM + h) * DH + sr)) * S_LEN + scg * 8;
  char* ldsK = (char*)&Kl[0][0][0] + w * 1024;
  char* ldsV = (char*)&Vl[0][0][0] + w * 1024;

  // Q fragments: B-operand, col q = lane&31, k = hi*8+j within slice ks
  bf16x8 qf[4];
  {
    const unsigned short* qrow =
        qb + (size_t)(tok0 + lq) * D_MODEL + h * DH + hi * 8;
#pragma unroll
    for (int ks = 0; ks < 4; ks++) qf[ks] = *(const bf16x8*)(qrow + ks * 16);
  }

  f32x16 ctx0, ctx1;
#pragma unroll
  for (int r = 0; r < 16; r++) { ctx0[r] = 0.f; ctx1[r] = 0.f; }
  float m_run = -1e30f, l_run = 0.f;

  const int nkt   = 2 * qi + 2;
  const int ndiag = 2 * qi;

  // prologue stage tile 0 into buf 0
  {
    const unsigned short* sK = kbase + (size_t)sr * D_MODEL;
    gload16(sK, ldsK);
    gload16(sK + (size_t)32 * D_MODEL, ldsK + 4096);
    gload16(vrow, ldsV);
    gload16(vrow + (size_t)32 * S_LEN, ldsV + 4096);
  }
  __syncthreads();

  for (int kt = 0; kt < nkt; ++kt) {
    const int cur = kt & 1;
    if (kt + 1 < nkt) {  // stage next tile into other buffer (T3 2-phase)
      const int nb = cur ^ 1;
      const unsigned short* sK = kbase + (size_t)((kt + 1) * 64 + sr) * D_MODEL;
      gload16(sK, ldsK + nb * 8192);
      gload16(sK + (size_t)32 * D_MODEL, ldsK + nb * 8192 + 4096);
      const unsigned short* sV = vrow + (kt + 1) * 64;
      gload16(sV, ldsV + nb * 8192);
      gload16(sV + (size_t)32 * S_LEN, ldsV + nb * 8192 + 4096);
    }

    // ---- S^T = K Q^T : lane holds q=lq, 16 kv per tile (+partner l^32) ----
    f32x16 s0, s1;
#pragma unroll
    for (int r = 0; r < 16; r++) { s0[r] = 0.f; s1[r] = 0.f; }
    __builtin_amdgcn_s_setprio(1);
#pragma unroll
    for (int ks = 0; ks < 4; ks++) {
      const int c = ((ks * 2 + hi) ^ (lq & 7)) * 8;
      bf16x8 k0 = *(const bf16x8*)&Kl[cur][lq][c];
      bf16x8 k1 = *(const bf16x8*)&Kl[cur][32 + lq][c];
      s0 = __builtin_amdgcn_mfma_f32_32x32x16_bf16(k0, qf[ks], s0, 0, 0, 0);
      s1 = __builtin_amdgcn_mfma_f32_32x32x16_bf16(k1, qf[ks], s1, 0, 0, 0);
    }
    __builtin_amdgcn_s_setprio(0);

    // ---- causal mask (diagonal tiles only; uniform branch) ----
    if (kt >= ndiag) {
      const int relq = qg0 + lq - kt * 64 - 4 * hi;
#pragma unroll
      for (int r = 0; r < 16; r++) {
        const int ko = (r & 3) + 8 * (r >> 2);
        s0[r] = (ko > relq) ? -1e30f : s0[r];
        s1[r] = (ko + 32 > relq) ? -1e30f : s1[r];
      }
    }

    // ---- row max: 31 local fmax + one cross-half exchange ----
    float pmax = s0[0];
#pragma unroll
    for (int r = 1; r < 16; r++) pmax = fmaxf(pmax, s0[r]);
#pragma unroll
    for (int r = 0; r < 16; r++) pmax = fmaxf(pmax, s1[r]);
    pmax = fmaxf(pmax, __shfl_xor(pmax, 32));

    // ---- defer-max rescale (T13, THR=8 in log2 domain) ----
    if (__any(pmax > m_run + 8.0f)) {
      const float mnew = fmaxf(m_run, pmax);
      const float al   = fexp2(m_run - mnew);
      m_run = mnew;
      l_run *= al;
#pragma unroll
      for (int r = 0; r < 16; r++) { ctx0[r] *= al; ctx1[r] *= al; }
    }

    // ---- P = exp2(S'-m), per-16kv slice: build P-frag in-reg, PV mfma ----
    float lsum = 0.f;
#pragma unroll
    for (int ks = 0; ks < 4; ks++) {
      float p[8];
#pragma unroll
      for (int j = 0; j < 8; j++) {
        const int r = (ks & 1) * 8 + j;
        const float sv = (ks < 2) ? s0[r] : s1[r];
        p[j] = fexp2(sv - m_run);
        lsum += p[j];
      }
      // pack pairs and exchange halves: lane needs kv slice hi*8..hi*8+7
      const unsigned w01 = cvt_pk_bf16(p[0], p[1]);
      const unsigned w23 = cvt_pk_bf16(p[2], p[3]);
      const unsigned w45 = cvt_pk_bf16(p[4], p[5]);
      const unsigned w67 = cvt_pk_bf16(p[6], p[7]);
      const unsigned x01 = __shfl_xor(w01, 32);
      const unsigned x23 = __shfl_xor(w23, 32);
      const unsigned x45 = __shfl_xor(w45, 32);
      const unsigned x67 = __shfl_xor(w67, 32);
      union { unsigned u[4]; bf16x8 v; } pw;
      pw.u[0] = hi ? x45 : w01;
      pw.u[1] = hi ? x67 : w23;
      pw.u[2] = hi ? w45 : x01;
      pw.u[3] = hi ? w67 : x23;
      const int c = ((ks * 2 + hi) ^ (lq & 7)) * 8;
      bf16x8 v0 = *(const bf16x8*)&Vl[cur][lq][c];
      bf16x8 v1 = *(const bf16x8*)&Vl[cur][32 + lq][c];
      __builtin_amdgcn_s_setprio(1);
      ctx0 = __builtin_amdgcn_mfma_f32_32x32x16_bf16(v0, pw.v, ctx0, 0, 0, 0);
      ctx1 = __builtin_amdgcn_mfma_f32_32x32x16_bf16(v1, pw.v, ctx1, 0, 0, 0);
      __builtin_amdgcn_s_setprio(0);
    }
    l_run += lsum;
    __syncthreads();  // drains staging vmcnt + guards buffer reuse
  }

  // ---- epilogue: normalize (per-lane scalar!), transpose via LDS, store ----
  const float lfull = l_run + __shfl_xor(l_run, 32);
  const float inv   = 1.0f / lfull;
#pragma unroll
  for (int rp = 0; rp < 8; rp++) {
    const int r  = rp * 2;
    const int d0 = (r & 3) + 8 * (r >> 2) + 4 * hi;  // even; pair (d0, d0+1)
    *(unsigned*)&Tl[w][lq][d0] = cvt_pk_bf16(ctx0[r] * inv, ctx0[r + 1] * inv);
    *(unsigned*)&Tl[w][lq][32 + d0] =
        cvt_pk_bf16(ctx1[r] * inv, ctx1[r + 1] * inv);
  }
  __syncthreads();
  // each lane stores 4 x 16B: q row = lane>>1, dh chunks (lane&1)*4 + 0..3
  const int q2 = lane >> 1;
#pragma unroll
  for (int i = 0; i < 4; i++) {
    const int ch = (lane & 1) * 4 + i;
    u16x8 vv = *(const u16x8*)&Tl[w][q2][ch * 8];
    *(u16x8*)&cx[(size_t)(tok0 + q2) * D_MODEL + h * DH + ch * 8] = vv;
  }
}

// ---------------------------------------------------------------------------
extern "C" void kernel_launch(void* const* d_in, const int* in_sizes, int n_in,
                              void* d_out, int out_size, void* d_ws,
                              size_t ws_size, hipStream_t stream) {
  const float* x  = (const float*)d_in[0];
  const float* Wq = (const float*)d_in[1];
  const float* Wk = (const float*)d_in[2];
  const float* Wv = (const float*)d_in[3];
  const float* Wo = (const float*)d_in[4];
  const float* bo = (const float*)d_in[5];
  float* out = (float*)d_out;

  // workspace (bf16 elements): xb 4M | wqb,wkb,wvb,wob 1M each | qb,kb,vt,cx 4M
  unsigned short* xb  = (unsigned short*)d_ws;
  unsigned short* wqb = xb  + (size_t)M_TOT * D_MODEL;
  unsigned short* wkb = wqb + (size_t)D_MODEL * D_MODEL;
  unsigned short* wvb = wkb + (size_t)D_MODEL * D_MODEL;
  unsigned short* wob = wvb + (size_t)D_MODEL * D_MODEL;
  unsigned short* qb  = wob + (size_t)D_MODEL * D_MODEL;
  unsigned short* kb  = qb  + (size_t)M_TOT * D_MODEL;
  unsigned short* vt  = kb  + (size_t)M_TOT * D_MODEL;
  unsigned short* cx  = vt  + (size_t)M_TOT * D_MODEL;

  to_bf16_all<<<4096, 256, 0, stream>>>(x, Wq, Wk, Wv, Wo, xb, wqb, wkb, wvb,
                                        wob);
  gemm_qkv<<<dim3(D_MODEL / 128, M_TOT / 128, 3), 256, 0, stream>>>(
      xb, wqb, wkb, wvb, qb, kb, vt);
  attn_v3<<<dim3(512), 256, 0, stream>>>(qb, kb, vt, cx);
  gemm_out<<<dim3(D_MODEL / 128, M_TOT / 128), 256, 0, stream>>>(cx, wob, out,
                                                                 bo);
}

// Round 5
// 122.119 us; speedup vs baseline: 2.4330x; 1.1299x over previous
//
#include <hip/hip_runtime.h>
#include <hip/hip_bf16.h>

// Problem constants (MultiHeadAttention, B=2, S=2048, D=1024, H=16)
#define B_SZ    2
#define S_LEN   2048
#define D_MODEL 1024
#define H_NUM   16
#define DH      64
#define M_TOT   (B_SZ * S_LEN)   // 4096 tokens

// scale = S^-0.5 (faithful bug) folded with log2(e) for exp2-domain softmax
#define QSCALE (0.022097086912079608f * 1.4426950408889634f)

typedef __attribute__((ext_vector_type(8)))  short          bf16x8;
typedef __attribute__((ext_vector_type(4)))  float          f32x4;
typedef __attribute__((ext_vector_type(16))) float          f32x16;
typedef __attribute__((ext_vector_type(8)))  unsigned short u16x8;
typedef __attribute__((ext_vector_type(4)))  unsigned short u16x4;

__device__ inline unsigned short f2bf(float f) {
  unsigned int u = __float_as_uint(f);
  u += 0x7fffu + ((u >> 16) & 1u);   // RNE (no NaN inputs here)
  return (unsigned short)(u >> 16);
}

__device__ inline float fexp2(float x) {
#if __has_builtin(__builtin_amdgcn_exp2f)
  return __builtin_amdgcn_exp2f(x);
#else
  return exp2f(x);
#endif
}

__device__ inline unsigned cvt_pk_bf16(float lo, float hi) {
  unsigned r;
  asm("v_cvt_pk_bf16_f32 %0, %1, %2" : "=v"(r) : "v"(lo), "v"(hi));
  return r;
}

// async global->LDS, 16B per lane. LDS dest = wave-uniform base + lane*16.
__device__ inline void gload16(const void* g, void* l) {
  __builtin_amdgcn_global_load_lds(
      (const __attribute__((address_space(1))) void*)g,
      (__attribute__((address_space(3))) void*)l, 16, 0, 0);
}

// ---------------------------------------------------------------------------
// fp32 -> bf16 conversion for x, Wq, Wk, Wv, Wo (8M elements, 8 per thread)
// ---------------------------------------------------------------------------
__global__ __launch_bounds__(256) void to_bf16_all(
    const float* __restrict__ x, const float* __restrict__ wq,
    const float* __restrict__ wk, const float* __restrict__ wv,
    const float* __restrict__ wo, unsigned short* __restrict__ xb,
    unsigned short* __restrict__ wqb, unsigned short* __restrict__ wkb,
    unsigned short* __restrict__ wvb, unsigned short* __restrict__ wob) {
  const size_t i = ((size_t)blockIdx.x * 256 + threadIdx.x) * 8;
  const float* src;
  unsigned short* dst;
  size_t off;
  if (i < 4194304)      { src = x;  dst = xb;  off = i; }
  else if (i < 5242880) { src = wq; dst = wqb; off = i - 4194304; }
  else if (i < 6291456) { src = wk; dst = wkb; off = i - 5242880; }
  else if (i < 7340032) { src = wv; dst = wvb; off = i - 6291456; }
  else                  { src = wo; dst = wob; off = i - 7340032; }
  f32x4 a = *(const f32x4*)(src + off);
  f32x4 b = *(const f32x4*)(src + off + 4);
  u16x8 o;
#pragma unroll
  for (int j = 0; j < 4; j++) { o[j] = f2bf(a[j]); o[4 + j] = f2bf(b[j]); }
  *(u16x8*)(dst + off) = o;
}

// ---------------------------------------------------------------------------
// bf16 NT-GEMM core: acc += A[128 rows @ mbase] * W[128 rows @ nbase]^T.
// Double-buffered global_load_lds(16) staging with counted vmcnt(4) + raw
// s_barrier pairs (prefetch stays in flight across barriers; no full drain).
// Linear LDS + XOR chunk swizzle (pre-swizzled source, swizzled read).
// ---------------------------------------------------------------------------
__device__ __forceinline__ void gemm_core(const unsigned short* __restrict__ A,
                                          const unsigned short* __restrict__ W,
                                          unsigned short (*Al)[128][32],
                                          unsigned short (*Bl)[128][32],
                                          int mbase, int nbase,
                                          f32x4 acc[4][4]) {
  const int tid  = threadIdx.x;
  const int lane = tid & 63;
  const int wid  = tid >> 6;
  const int wr   = wid >> 1, wc = wid & 1;
  const int g    = lane >> 4, lr = lane & 15;

  const int r0 = tid >> 2;                        // 0..63 staging row
  const int cg = (tid & 3) ^ ((tid >> 3) & 3);    // swizzled source chunk

  const unsigned short* Abase = A + (size_t)(mbase + r0) * D_MODEL + cg * 8;
  const unsigned short* Wbase = W + (size_t)(nbase + r0) * D_MODEL + cg * 8;
  char* ldsA0 = (char*)Al + wid * 1024;  // buffer stride 8192
  char* ldsB0 = (char*)Bl + wid * 1024;

  // prologue: tile 0 -> buf 0
  gload16(Abase, ldsA0);
  gload16(Abase + (size_t)64 * D_MODEL, ldsA0 + 4096);
  gload16(Wbase, ldsB0);
  gload16(Wbase + (size_t)64 * D_MODEL, ldsB0 + 4096);

  const int NKT = D_MODEL / 32;
  for (int kt = 0; kt < NKT; ++kt) {
    const int cur = kt & 1;
    if (kt + 1 < NKT) {  // prefetch next tile into other buffer
      const unsigned short* As = Abase + (kt + 1) * 32;
      const unsigned short* Ws = Wbase + (kt + 1) * 32;
      char* la = ldsA0 + (cur ^ 1) * 8192;
      char* lb = ldsB0 + (cur ^ 1) * 8192;
      gload16(As, la);
      gload16(As + (size_t)64 * D_MODEL, la + 4096);
      gload16(Ws, lb);
      gload16(Ws + (size_t)64 * D_MODEL, lb + 4096);
      asm volatile("s_waitcnt vmcnt(4)" ::: "memory");  // tile kt landed
    } else {
      asm volatile("s_waitcnt vmcnt(0)" ::: "memory");
    }
    __builtin_amdgcn_s_barrier();

    bf16x8 af[4], bfr[4];
#pragma unroll
    for (int i = 0; i < 4; i++) {
      const int ra = wr * 64 + i * 16 + lr;
      af[i] = *(const bf16x8*)&Al[cur][ra][(g ^ ((ra >> 1) & 3)) * 8];
      const int rb = wc * 64 + i * 16 + lr;
      bfr[i] = *(const bf16x8*)&Bl[cur][rb][(g ^ ((rb >> 1) & 3)) * 8];
    }
    __builtin_amdgcn_s_setprio(1);
#pragma unroll
    for (int i = 0; i < 4; i++)
#pragma unroll
      for (int j = 0; j < 4; j++)
        acc[i][j] = __builtin_amdgcn_mfma_f32_16x16x32_bf16(af[i], bfr[j],
                                                            acc[i][j], 0, 0, 0);
    __builtin_amdgcn_s_setprio(0);
    asm volatile("" ::: "memory");
    __builtin_amdgcn_s_barrier();  // buf[cur] free for next prefetch
  }
}

// ---------------------------------------------------------------------------
// Fused Q/K/V projection. grid (N/128, M/128, 3); z picks weight + epilogue.
// z=0 -> Q bf16 [M][D] PRE-SCALED by QSCALE; z=1 -> K bf16 [M][D];
// z=2 -> V transposed Vt[((b*H+h)*DH+d)*S + s].
// ---------------------------------------------------------------------------
__global__ __launch_bounds__(256) void gemm_qkv(
    const unsigned short* __restrict__ xb, const unsigned short* __restrict__ wqb,
    const unsigned short* __restrict__ wkb, const unsigned short* __restrict__ wvb,
    unsigned short* __restrict__ qb, unsigned short* __restrict__ kb,
    unsigned short* __restrict__ vt) {
  __shared__ unsigned short Al[2][128][32];
  __shared__ unsigned short Bl[2][128][32];
  const int z = blockIdx.z;
  const unsigned short* W = (z == 0) ? wqb : (z == 1) ? wkb : wvb;
  unsigned short* dst = (z == 0) ? qb : (z == 1) ? kb : vt;
  const float sc = (z == 0) ? QSCALE : 1.0f;

  f32x4 acc[4][4];
#pragma unroll
  for (int i = 0; i < 4; i++)
#pragma unroll
    for (int j = 0; j < 4; j++) acc[i][j] = (f32x4){0.f, 0.f, 0.f, 0.f};

  const int mbase = blockIdx.y * 128, nbase = blockIdx.x * 128;
  gemm_core(xb, W, Al, Bl, mbase, nbase, acc);

  const int lane = threadIdx.x & 63, wid = threadIdx.x >> 6;
  const int wr = wid >> 1, wc = wid & 1, g = lane >> 4, lr = lane & 15;
#pragma unroll
  for (int i = 0; i < 4; i++) {
#pragma unroll
    for (int j = 0; j < 4; j++) {
      const int mg0 = mbase + wr * 64 + i * 16 + g * 4;  // + r
      const int ng  = nbase + wc * 64 + j * 16 + lr;
      if (z < 2) {
#pragma unroll
        for (int r = 0; r < 4; r++)
          dst[(size_t)(mg0 + r) * D_MODEL + ng] = f2bf(acc[i][j][r] * sc);
      } else {
        const int hh = ng >> 6, dd = ng & 63;
        const int bb = mg0 >> 11, ss = mg0 & 2047;  // mg0 mult of 4
        u16x4 pk;
#pragma unroll
        for (int r = 0; r < 4; r++) pk[r] = f2bf(acc[i][j][r]);
        *(u16x4*)&dst[((size_t)((bb * H_NUM + hh) * DH + dd)) * S_LEN + ss] = pk;
      }
    }
  }
}

// ---------------------------------------------------------------------------
// Output projection: out[M][D] fp32 = cx * Wo^T + bo
// ---------------------------------------------------------------------------
__global__ __launch_bounds__(256) void gemm_out(
    const unsigned short* __restrict__ cx, const unsigned short* __restrict__ wob,
    float* __restrict__ out, const float* __restrict__ bo) {
  __shared__ unsigned short Al[2][128][32];
  __shared__ unsigned short Bl[2][128][32];
  f32x4 acc[4][4];
#pragma unroll
  for (int i = 0; i < 4; i++)
#pragma unroll
    for (int j = 0; j < 4; j++) acc[i][j] = (f32x4){0.f, 0.f, 0.f, 0.f};

  const int mbase = blockIdx.y * 128, nbase = blockIdx.x * 128;
  gemm_core(cx, wob, Al, Bl, mbase, nbase, acc);

  const int lane = threadIdx.x & 63, wid = threadIdx.x >> 6;
  const int wr = wid >> 1, wc = wid & 1, g = lane >> 4, lr = lane & 15;
#pragma unroll
  for (int i = 0; i < 4; i++) {
#pragma unroll
    for (int j = 0; j < 4; j++) {
      const int mg0 = mbase + wr * 64 + i * 16 + g * 4;
      const int ng  = nbase + wc * 64 + j * 16 + lr;
      const float bv = bo[ng];
#pragma unroll
      for (int r = 0; r < 4; r++)
        out[(size_t)(mg0 + r) * D_MODEL + ng] = acc[i][j][r] + bv;
    }
  }
}

// ---------------------------------------------------------------------------
// Causal flash attention, swapped-operand 32x32 structure.
// grid = 512 1-D blocks; 4 waves/block, each wave owns 32 q-rows.
// bid<256 -> qtiles 8..15, bid>=256 -> qtiles 7..0 (balanced CU pairing).
// S^T = mfma(K, Q): lane owns full P-row of q = lane&31 (partner l^32).
// ctx^T = mfma(Vt, P): normalize/rescale are per-lane scalars.
// Counted-vmcnt double-buffered K/V staging (T3/T4): prefetch stays in
// flight across barriers. Transpose buffer Tl overlays the K/V LDS.
// ---------------------------------------------------------------------------
__global__ __launch_bounds__(256) void attn_v3(
    const unsigned short* __restrict__ qb, const unsigned short* __restrict__ kb,
    const unsigned short* __restrict__ vt, unsigned short* __restrict__ cx) {
  // 32 KiB: K buf0 | K buf1 | V buf0 | V buf1, each [64][64] bf16 (8 KiB).
  // After the loop, the first 18.4 KiB are reused as Tl[4][32][72].
  __shared__ alignas(16) char smem[32768];

  const int tid  = threadIdx.x;
  const int lane = tid & 63;
  const int w    = tid >> 6;
  const int hi   = lane >> 5;
  const int lq   = lane & 31;
  const int bid  = blockIdx.x;
  const int qi   = (bid < 256) ? (8 + (bid >> 5)) : (7 - ((bid - 256) >> 5));
  const int bh   = bid & 31;
  const int b    = bh >> 4, h = bh & 15;

  const int qg0  = qi * 128 + w * 32;   // wave's q base within sequence
  const int tok0 = b * S_LEN + qg0;

  // staging: thread t -> row t>>3 (+32 for 2nd issue), chunk t&7 swizzled
  const int sr  = tid >> 3;
  const int scg = (tid & 7) ^ (sr & 7);
  const unsigned short* kbase =
      kb + (size_t)(b * S_LEN) * D_MODEL + h * DH + scg * 8;
  const unsigned short* vrow =
      vt + ((size_t)((b * H_NUM + h) * DH + sr)) * S_LEN + scg * 8;
  char* ldsK0 = smem + w * 1024;           // + buf*8192
  char* ldsV0 = smem + 16384 + w * 1024;   // + buf*8192

  // Q fragments: B-operand, col q = lane&31, k = hi*8+j within slice ks
  bf16x8 qf[4];
  {
    const unsigned short* qrow =
        qb + (size_t)(tok0 + lq) * D_MODEL + h * DH + hi * 8;
#pragma unroll
    for (int ks = 0; ks < 4; ks++) qf[ks] = *(const bf16x8*)(qrow + ks * 16);
  }

  f32x16 ctx0, ctx1;
#pragma unroll
  for (int r = 0; r < 16; r++) { ctx0[r] = 0.f; ctx1[r] = 0.f; }
  float m_run = -1e30f, l_run = 0.f;

  const int nkt   = 2 * qi + 2;
  const int ndiag = 2 * qi;

  // prologue: stage tile 0 into buf 0 (4 loads)
  {
    const unsigned short* sK = kbase + (size_t)sr * D_MODEL;
    gload16(sK, ldsK0);
    gload16(sK + (size_t)32 * D_MODEL, ldsK0 + 4096);
    gload16(vrow, ldsV0);
    gload16(vrow + (size_t)32 * S_LEN, ldsV0 + 4096);
  }

  for (int kt = 0; kt < nkt; ++kt) {
    const int cur = kt & 1;
    if (kt + 1 < nkt) {  // prefetch next tile into other buffer
      const int nb = cur ^ 1;
      const unsigned short* sK = kbase + (size_t)((kt + 1) * 64 + sr) * D_MODEL;
      gload16(sK, ldsK0 + nb * 8192);
      gload16(sK + (size_t)32 * D_MODEL, ldsK0 + nb * 8192 + 4096);
      const unsigned short* sV = vrow + (kt + 1) * 64;
      gload16(sV, ldsV0 + nb * 8192);
      gload16(sV + (size_t)32 * S_LEN, ldsV0 + nb * 8192 + 4096);
      asm volatile("s_waitcnt vmcnt(4)" ::: "memory");  // tile kt landed
    } else {
      asm volatile("s_waitcnt vmcnt(0)" ::: "memory");
    }
    __builtin_amdgcn_s_barrier();

    const char* Kc = smem + cur * 8192;
    const char* Vc = smem + 16384 + cur * 8192;

    // ---- S^T = K Q^T : lane holds q=lq, 32 of 64 kv (partner l^32) ----
    f32x16 s0, s1;
#pragma unroll
    for (int r = 0; r < 16; r++) { s0[r] = 0.f; s1[r] = 0.f; }
    __builtin_amdgcn_s_setprio(1);
#pragma unroll
    for (int ks = 0; ks < 4; ks++) {
      const int c = ((ks * 2 + hi) ^ (lq & 7)) * 16;  // byte offset
      bf16x8 k0 = *(const bf16x8*)(Kc + lq * 128 + c);
      bf16x8 k1 = *(const bf16x8*)(Kc + (32 + lq) * 128 + c);
      s0 = __builtin_amdgcn_mfma_f32_32x32x16_bf16(k0, qf[ks], s0, 0, 0, 0);
      s1 = __builtin_amdgcn_mfma_f32_32x32x16_bf16(k1, qf[ks], s1, 0, 0, 0);
    }
    __builtin_amdgcn_s_setprio(0);

    // ---- causal mask (diagonal tiles only; uniform branch) ----
    if (kt >= ndiag) {
      const int relq = qg0 + lq - kt * 64 - 4 * hi;
#pragma unroll
      for (int r = 0; r < 16; r++) {
        const int ko = (r & 3) + 8 * (r >> 2);
        s0[r] = (ko > relq) ? -1e30f : s0[r];
        s1[r] = (ko + 32 > relq) ? -1e30f : s1[r];
      }
    }

    // ---- row max: 31 local fmax + one cross-half exchange ----
    float pmax = s0[0];
#pragma unroll
    for (int r = 1; r < 16; r++) pmax = fmaxf(pmax, s0[r]);
#pragma unroll
    for (int r = 0; r < 16; r++) pmax = fmaxf(pmax, s1[r]);
    pmax = fmaxf(pmax, __shfl_xor(pmax, 32));

    // ---- defer-max rescale (T13, THR=8 in log2 domain) ----
    if (__any(pmax > m_run + 8.0f)) {
      const float mnew = fmaxf(m_run, pmax);
      const float al   = fexp2(m_run - mnew);
      m_run = mnew;
      l_run *= al;
#pragma unroll
      for (int r = 0; r < 16; r++) { ctx0[r] *= al; ctx1[r] *= al; }
    }

    // ---- P = exp2(S'-m) per 16-kv slice: pack in-reg, PV mfma ----
    float lsum = 0.f;
#pragma unroll
    for (int ks = 0; ks < 4; ks++) {
      float p[8];
#pragma unroll
      for (int j = 0; j < 8; j++) {
        const int r = (ks & 1) * 8 + j;
        const float sv = (ks < 2) ? s0[r] : s1[r];
        p[j] = fexp2(sv - m_run);
        lsum += p[j];
      }
      const unsigned w01 = cvt_pk_bf16(p[0], p[1]);
      const unsigned w23 = cvt_pk_bf16(p[2], p[3]);
      const unsigned w45 = cvt_pk_bf16(p[4], p[5]);
      const unsigned w67 = cvt_pk_bf16(p[6], p[7]);
      const unsigned x01 = __shfl_xor(w01, 32);
      const unsigned x23 = __shfl_xor(w23, 32);
      const unsigned x45 = __shfl_xor(w45, 32);
      const unsigned x67 = __shfl_xor(w67, 32);
      union { unsigned u[4]; bf16x8 v; } pw;
      pw.u[0] = hi ? x45 : w01;
      pw.u[1] = hi ? x67 : w23;
      pw.u[2] = hi ? w45 : x01;
      pw.u[3] = hi ? w67 : x23;
      const int c = ((ks * 2 + hi) ^ (lq & 7)) * 16;  // byte offset
      bf16x8 v0 = *(const bf16x8*)(Vc + lq * 128 + c);
      bf16x8 v1 = *(const bf16x8*)(Vc + (32 + lq) * 128 + c);
      __builtin_amdgcn_s_setprio(1);
      ctx0 = __builtin_amdgcn_mfma_f32_32x32x16_bf16(v0, pw.v, ctx0, 0, 0, 0);
      ctx1 = __builtin_amdgcn_mfma_f32_32x32x16_bf16(v1, pw.v, ctx1, 0, 0, 0);
      __builtin_amdgcn_s_setprio(0);
    }
    l_run += lsum;
    asm volatile("" ::: "memory");
    __builtin_amdgcn_s_barrier();  // buf[cur] free for next prefetch
  }

  // ---- epilogue: normalize (per-lane scalar), transpose via LDS, store ----
  // Tl overlays K/V buffers; per-wave region, same-wave write->read only.
  unsigned short (*Tl)[32][72] = (unsigned short (*)[32][72])smem;
  const float lfull = l_run + __shfl_xor(l_run, 32);
  const float inv   = 1.0f / lfull;
#pragma unroll
  for (int rp = 0; rp < 8; rp++) {
    const int r  = rp * 2;
    const int d0 = (r & 3) + 8 * (r >> 2) + 4 * hi;  // even; pair (d0, d0+1)
    *(unsigned*)&Tl[w][lq][d0] = cvt_pk_bf16(ctx0[r] * inv, ctx0[r + 1] * inv);
    *(unsigned*)&Tl[w][lq][32 + d0] =
        cvt_pk_bf16(ctx1[r] * inv, ctx1[r + 1] * inv);
  }
  __builtin_amdgcn_s_waitcnt(0);  // drain lgkm (ds_write) before read-back
  // each lane stores 4 x 16B: q row = lane>>1, dh chunks (lane&1)*4 + 0..3
  const int q2 = lane >> 1;
#pragma unroll
  for (int i = 0; i < 4; i++) {
    const int ch = (lane & 1) * 4 + i;
    u16x8 vv = *(const u16x8*)&Tl[w][q2][ch * 8];
    *(u16x8*)&cx[(size_t)(tok0 + q2) * D_MODEL + h * DH + ch * 8] = vv;
  }
}

// ---------------------------------------------------------------------------
extern "C" void kernel_launch(void* const* d_in, const int* in_sizes, int n_in,
                              void* d_out, int out_size, void* d_ws,
                              size_t ws_size, hipStream_t stream) {
  const float* x  = (const float*)d_in[0];
  const float* Wq = (const float*)d_in[1];
  const float* Wk = (const float*)d_in[2];
  const float* Wv = (const float*)d_in[3];
  const float* Wo = (const float*)d_in[4];
  const float* bo = (const float*)d_in[5];
  float* out = (float*)d_out;

  // workspace (bf16 elements): xb 4M | wqb,wkb,wvb,wob 1M each | qb,kb,vt,cx 4M
  unsigned short* xb  = (unsigned short*)d_ws;
  unsigned short* wqb = xb  + (size_t)M_TOT * D_MODEL;
  unsigned short* wkb = wqb + (size_t)D_MODEL * D_MODEL;
  unsigned short* wvb = wkb + (size_t)D_MODEL * D_MODEL;
  unsigned short* wob = wvb + (size_t)D_MODEL * D_MODEL;
  unsigned short* qb  = wob + (size_t)D_MODEL * D_MODEL;
  unsigned short* kb  = qb  + (size_t)M_TOT * D_MODEL;
  unsigned short* vt  = kb  + (size_t)M_TOT * D_MODEL;
  unsigned short* cx  = vt  + (size_t)M_TOT * D_MODEL;

  to_bf16_all<<<4096, 256, 0, stream>>>(x, Wq, Wk, Wv, Wo, xb, wqb, wkb, wvb,
                                        wob);
  gemm_qkv<<<dim3(D_MODEL / 128, M_TOT / 128, 3), 256, 0, stream>>>(
      xb, wqb, wkb, wvb, qb, kb, vt);
  attn_v3<<<dim3(512), 256, 0, stream>>>(qb, kb, vt, cx);
  gemm_out<<<dim3(D_MODEL / 128, M_TOT / 128), 256, 0, stream>>>(cx, wob, out,
                                                                 bo);
}